// Round 4
// baseline (1744.215 us; speedup 1.0000x reference)
//
#include <hip/hip_runtime.h>
#include <math.h>

namespace {

constexpr int kB = 2, kH = 16, kN = 8192, kHD = 128, kJ = 20;
constexpr int kTQ = 64;                         // queries per sub-tile (4 lanes/query, 256 thr)
constexpr int kST = 4;                          // sub-tiles per block -> 256 queries/block
constexpr int kQB = kTQ * kST;                  // 256 queries per block
constexpr int kNT = kN / kQB;                   // 32 block-tiles per (b,h)
constexpr int kNWG = kB * kH * kNT;             // 1024 workgroups
constexpr int kNXCD = 8;
constexpr int kChunk = kNWG / kNXCD;            // 128 contiguous blocks per XCD
constexpr float kScale = 0.08838834764831845f;  // 1/sqrt(128)

typedef float f4 __attribute__((ext_vector_type(4)));

// Lane mapping: t>>2 = query, t&3 = part. Lane `part` owns float4 chunks
// {i*4 + part}: each wave load covers a contiguous 64B span per 4-lane
// group (minimum cache lines per instruction).
//
// Multi-tile blocks (round-4 change): round-0 counters showed 300KB
// fetched per 64-query block = 261 unique k/v rows for 64 rows of ideal
// traffic -> 4x halo over-fetch (union of the 20 offset windows). Halo is
// ~constant in tile size, so each block now walks 4 consecutive 64-query
// sub-tiles: sub-tiles 1-3 re-hit the halo rows in L1/L2 and only add
// ~64 new rows each. Predicted fetch ~650MB vs round-0 1.23GB.
//
// NT loads/stores REMOVED (round-3 post-mortem): NT stores bypassed L2
// write-combining -> partial-line RMW at HBM, WRITE_SIZE 237MB->945MB,
// +324us. Plain cached stores merge the 64B chunks into full lines.
//
// __launch_bounds__(256,4): cap 128 VGPR (compiler lands at 64).
// (256,8) forced VGPR=32 and spilled (round-2: WRITE 1.86GB, 2.8x slower).
__global__ __launch_bounds__(256, 4)
void dsqg_fwd(const float* __restrict__ q, const float* __restrict__ k,
              const float* __restrict__ v, const float* __restrict__ pb,
              const float* __restrict__ se, float* __restrict__ out) {
  constexpr int OFFS[kJ] = {1, 2, 3, 4, 5, 6, 7, 8, 9, 11,
                            13, 15, 16, 23, 32, 64, 128, 256, 512, 1024};
  __shared__ float s_se[kJ * kHD];  // 10 KB
  __shared__ float s_pb[kJ];

  const int t = threadIdx.x;
  const int lin = blockIdx.x;
  // XCD-contiguous bijection: XCD x owns ids [x*128,(x+1)*128) and walks
  // them in ascending order (slice-major, ascending n).
  const int swz = (lin & (kNXCD - 1)) * kChunk + (lin >> 3);
  const int bh = swz >> 5;                  // swz / kNT (kNT == 32)
  const int tile0 = (swz & (kNT - 1)) * kQB;
  const int h = bh & (kH - 1);
  const int part = t & 3;

  for (int i = t; i < kJ * kHD; i += 256) s_se[i] = se[i];
  if (t < kJ) s_pb[t] = pb[t * kH + h];
  __syncthreads();

  const size_t base = (size_t)bh * kN * kHD;

  for (int s = 0; s < kST; ++s) {
    const int n = tile0 + s * kTQ + (t >> 2);

    const f4* qrow = (const f4*)(q + base + (size_t)n * kHD);
    f4 rq[8];
#pragma unroll
    for (int i = 0; i < 8; ++i) rq[i] = qrow[i * 4 + part];

    // ---- Phase A: s_j = sc*(q.(k[n-dj]+se_j)) + pb[j][h], -inf if n<dj
    float sc[kJ];
#pragma unroll
    for (int j = 0; j < kJ; ++j) {
      const int delta = OFFS[j];
      int kr = n - delta;
      kr = kr < 0 ? 0 : kr;
      const f4* krow = (const f4*)(k + base + (size_t)kr * kHD);
      const f4* srow = (const f4*)(s_se + j * kHD);
      float acc = 0.f;
#pragma unroll
      for (int i = 0; i < 8; ++i) {
        f4 kv = krow[i * 4 + part];
        f4 sv = srow[i * 4 + part];
        acc += rq[i].x * (kv.x + sv.x);
        acc += rq[i].y * (kv.y + sv.y);
        acc += rq[i].z * (kv.z + sv.z);
        acc += rq[i].w * (kv.w + sv.w);
      }
      acc += __shfl_xor(acc, 1);
      acc += __shfl_xor(acc, 2);
      const float sj = acc * kScale + s_pb[j];
      sc[j] = (n >= delta) ? sj : -INFINITY;
    }

    // ---- softmax over J (redundant in the 4 lanes)
    float m = -INFINITY;
#pragma unroll
    for (int j = 0; j < kJ; ++j) m = fmaxf(m, sc[j]);
    const float msafe = (m == -INFINITY) ? 0.f : m;
    float l = 0.f;
#pragma unroll
    for (int j = 0; j < kJ; ++j) {
      const float e = (sc[j] == -INFINITY) ? 0.f : __expf(sc[j] - msafe);
      sc[j] = e;  // reuse: sc now holds unnormalized p
      l += e;
    }
    const float inv = (l > 0.f) ? 1.f / l : 0.f;  // n==0 -> zero output

    // ---- Phase B: out = sum_j p_j * v[n-dj]
    f4 o[8];
#pragma unroll
    for (int i = 0; i < 8; ++i) o[i] = (f4)(0.f);
#pragma unroll
    for (int j = 0; j < kJ; ++j) {
      const float pj = sc[j] * inv;
      int vr = n - OFFS[j];
      vr = vr < 0 ? 0 : vr;
      const f4* vrow = (const f4*)(v + base + (size_t)vr * kHD);
#pragma unroll
      for (int i = 0; i < 8; ++i) {
        f4 vv = vrow[i * 4 + part];
        o[i] += pj * vv;
      }
    }
    f4* orow = (f4*)(out + base + (size_t)n * kHD);
#pragma unroll
    for (int i = 0; i < 8; ++i) orow[i * 4 + part] = o[i];
  }
}

}  // namespace

extern "C" void kernel_launch(void* const* d_in, const int* in_sizes, int n_in,
                              void* d_out, int out_size, void* d_ws, size_t ws_size,
                              hipStream_t stream) {
  const float* q = (const float*)d_in[0];
  const float* k = (const float*)d_in[1];
  const float* v = (const float*)d_in[2];
  const float* pb = (const float*)d_in[3];   // [J,H]
  const float* se = (const float*)d_in[4];   // [J,HD]
  float* out = (float*)d_out;

  dim3 grid(kNWG);  // 1024 blocks, 1D, XCD-swizzled in-kernel
  dsqg_fwd<<<grid, 256, 0, stream>>>(q, k, v, pb, se, out);
}